// Round 3
// baseline (173.825 us; speedup 1.0000x reference)
//
#include <hip/hip_runtime.h>
#include <stdint.h>

// Round 13: 2D wave tiling for load locality.
// fp32 in / fp32 out. d_out = box, boxy (each [8,1,1024,2048]).
// gt_up[y,x] == gt[y>>3, x>>3] (never materialized).
//
// vs r12 (quad-gather + zero-seg, both kept, inner loop byte-identical):
// lane->pixel map changed from 1D (wave = 512 contiguous px of ONE row,
// cross-lane iy spread = 256*t3 upsampled rows -> 64 distinct cache lines
// per wave-load) to 2D (wave = 8 rows x 64 px: lx=lane&7 x-segment,
// ly=lane>>3 row; block = 4 waves = 32 rows x 64 px). Wave input footprint
// drops to ~(8|t0|+2)x(4|t3|+|t4|+2) quads total -> ~5-8x fewer L1 line
// transactions + intra-wave reuse. Stores remain full-line coalesced
// (8 x 128B contiguous segments per store instruction).

typedef float vfloat4 __attribute__((ext_vector_type(4)));

constexpr int BATCH = 8;
constexpr int HI = 128, WI = 256;
constexpr int HO = 1024, WO = 2048;
constexpr size_t NPIX = (size_t)BATCH * HO * WO;   // 16777216 per output

// Quad image: Q[y+1][x+1] = (P[y][x], P[y][x+1], P[y+1][x], P[y+1][x+1]),
// P = zero-padded gt. Row index cy0+1 in [0,129], col cx0+1 in [0,257].
constexpr int QH = HI + 2;
constexpr int QW = WI + 2;
constexpr size_t QIMG = (size_t)QH * QW;           // quads per image

__global__ __launch_bounds__(256) void pad4_kernel(
    const float* __restrict__ gt, vfloat4* __restrict__ Q)
{
    const int i = blockIdx.x * 256 + threadIdx.x;  // over BATCH*QIMG
    if (i >= (int)(BATCH * QIMG)) return;
    const int b = i / (int)QIMG;
    const int r = i - b * (int)QIMG;
    const int y = r / QW - 1;                      // [-1, HI]
    const int x = r - (r / QW) * QW - 1;           // [-1, WI]
    const float* __restrict__ g = gt + (size_t)b * (HI * WI);
    auto val = [&](int yy, int xx) -> float {
        return (yy >= 0 && yy < HI && xx >= 0 && xx < WI)
                   ? g[yy * WI + xx] : 0.0f;
    };
    vfloat4 q = { val(y, x), val(y, x + 1), val(y + 1, x), val(y + 1, x + 1) };
    Q[i] = q;
}

__global__ __launch_bounds__(256) void stn_kernel(
    const float* __restrict__ gt,     // [B, HI, WI] (boxy path)
    const float* __restrict__ theta,  // [B, 6]
    const vfloat4* __restrict__ Q,    // quad images in d_ws
    float* __restrict__ out)          // [2, B, HO, WO] f32
{
    // Block tile: 32 rows x 64 px. Grid = 8 b * 32 ytiles * 32 xtiles = 8192.
    const int bid = blockIdx.x;
    const int xt = bid & 31;               // x-tile (64 px each)
    const int yt = (bid >> 5) & 31;        // y-tile (32 rows each)
    const int b  = bid >> 10;
    const int tx = threadIdx.x & 7;        // 8-px segment within tile
    const int ty = threadIdx.x >> 3;       // row within tile (0..31)
    const int h  = yt * 32 + ty;
    const int w0 = xt * 64 + tx * 8;
    const int row = (b << 10) + h;         // b*HO + h

    const float* tb = theta + b * 6;
    const float t0 = tb[0], t1 = tb[1], t2 = tb[2];
    const float t3 = tb[3], t4 = tb[4], t5 = tb[5];
    const float* __restrict__ gtb = gt + b * (HI * WI);
    const vfloat4* __restrict__ Qb = Q + (size_t)b * QIMG;

    const float ys = (h + 0.5f) * (2.0f / (float)HO) - 1.0f;

    // ---------------- boxy: scalar per thread, broadcast to 8 px ----------------
    {
        const float gy2 = t4 * ys + t5;
        const float iy = ((gy2 + 1.0f) * (float)HO - 1.0f) * 0.5f;
        const float fy = floorf(iy);
        const float wy = iy - fy;
        const float vy0 = (fy >= 0.0f && fy <= (float)(HO - 1)) ? 1.0f : 0.0f;
        const float vy1 = (fy >= -1.0f && fy <= (float)(HO - 2)) ? 1.0f : 0.0f;
        const int y0 = ((int)fminf(fmaxf(fy,        0.0f), (float)(HO - 1))) >> 3;
        const int y1 = ((int)fminf(fmaxf(fy + 1.0f, 0.0f), (float)(HO - 1))) >> 3;
        const int cell = w0 >> 3;          // input cell column
        const float s0 = gtb[y0 * WI + cell];
        const float s1 = gtb[y1 * WI + cell];
        const float byv = s0 * ((1.0f - wy) * vy0) + s1 * (wy * vy1);
        const vfloat4 vb = {byv, byv, byv, byv};
        vfloat4* dst = reinterpret_cast<vfloat4*>(out + NPIX + (size_t)row * WO + w0);
        __builtin_nontemporal_store(vb, dst);
        __builtin_nontemporal_store(vb, dst + 1);
    }

    // ---------------- box: 8 px bilinear via one quad load each ----------------
    const float xn0 = (w0 + 0.5f) * (2.0f / (float)WO) - 1.0f;
    const float gx0 = t0 * xn0 + (t1 * ys + t2);
    const float gy0 = t3 * xn0 + (t4 * ys + t5);
    float ix = ((gx0 + 1.0f) * (float)WO - 1.0f) * 0.5f;   // step t0 per px
    float iy = ((gy0 + 1.0f) * (float)HO - 1.0f) * 0.5f;   // step t3/2 per px
    const float dix = t0;
    const float diy = 0.5f * t3;

    // Zero-segment test: pixel is exactly 0 iff ix<-1 | ix>=WO | iy<-1 | iy>=HO.
    // ix,iy affine in p -> endpoint checks prove the whole 8-px segment zero.
    const float ixe = ix + 7.0f * dix;
    const float iye = iy + 7.0f * diy;
    const bool segzero =
        (fmaxf(ix, ixe) < -1.0f) || (fminf(ix, ixe) >= (float)WO) ||
        (fmaxf(iy, iye) < -1.0f) || (fminf(iy, iye) >= (float)HO);

    float px[8];
    if (segzero) {
#pragma unroll
        for (int p = 0; p < 8; ++p) px[p] = 0.0f;
    } else {
#pragma unroll
        for (int p = 0; p < 8; ++p) {
            const float fx = floorf(ix), fy = floorf(iy);
            const float wx = ix - fx,    wy = iy - fy;
            const int xi = (int)fx, yi = (int)fy;       // cvt saturates at extremes
            const int cx0 = min(max(xi >> 3,       -1), WI);
            const int cx1 = min(max((xi + 1) >> 3, -1), WI);
            const int cy0 = min(max(yi >> 3,       -1), HI);
            const int cy1 = min(max((yi + 1) >> 3, -1), HI);
            const vfloat4 q = Qb[(cy0 + 1) * QW + (cx0 + 1)];
            const bool cxe = (cx1 == cx0);
            const bool cye = (cy1 == cy0);
            const float a  = q.x;
            const float bb = cxe ? q.x : q.y;           // P[cy0][cx1]
            const float c  = cye ? q.x : q.z;           // P[cy1][cx0]
            const float dl = cxe ? q.z : q.w;
            const float d  = cye ? bb  : dl;            // P[cy1][cx1]
            const float h0 = fmaf(wx, bb - a, a);
            const float h1 = fmaf(wx, d - c,  c);
            px[p] = fmaf(wy, h1 - h0, h0);
            ix += dix; iy += diy;
        }
    }
    vfloat4* dst = reinterpret_cast<vfloat4*>(out + (size_t)row * WO + w0);
    const vfloat4 v0 = {px[0], px[1], px[2], px[3]};
    const vfloat4 v1 = {px[4], px[5], px[6], px[7]};
    __builtin_nontemporal_store(v0, dst);
    __builtin_nontemporal_store(v1, dst + 1);
}

extern "C" void kernel_launch(void* const* d_in, const int* in_sizes, int n_in,
                              void* d_out, int out_size, void* d_ws, size_t ws_size,
                              hipStream_t stream) {
    const float* gt    = (const float*)d_in[0];
    const float* theta = (const float*)d_in[1];
    float* out = (float*)d_out;
    vfloat4* Q = (vfloat4*)d_ws;   // 8*130*258*16 B ~= 4.3 MB << ws_size

    const int qN = (int)(BATCH * QIMG);
    pad4_kernel<<<(qN + 255) / 256, 256, 0, stream>>>(gt, Q);
    stn_kernel<<<BATCH * HO, 256, 0, stream>>>(gt, theta, Q, out);
}

// Round 4
// 169.885 us; speedup vs baseline: 1.0232x; 1.0232x over previous
//
#include <hip/hip_runtime.h>
#include <stdint.h>

// Round 14: latency-pipelined box loop + segsafe de-clamp.
// Base = r12 (1D lane map, quad-gather, zero-seg; best measured 168.4 us).
// fp32 in / fp32 out. d_out = box, boxy (each [8,1,1024,2048]).
// gt_up[y,x] == gt[y>>3, x>>3] (never materialized).
//
// vs r12:
//  (1) box inner loop split into two passes: pass1 computes all 8 coords
//      independently (fmaf(p,dix,ix0) - no serial ix+=dix chain) and issues
//      all 8 quad loads into q[8] (static indices -> registers); pass2
//      blends. 8 loads in flight per lane instead of 1 -> L2 latency
//      amortized 8x.
//  (2) segsafe fast path: if all 8 px have ix in [-1,WO) and iy in [-1,HO)
//      (exact endpoint test, coords affine in p), then cx0=xi>>3,
//      cx1=(xi+1)>>3, cy0=yi>>3, cy1=(yi+1)>>3 are already in [-1,WI]/[-1,HI]
//      (arith shift: -1>>3 == -1; 2048>>3 == 256 == pad col) -> the 8
//      min/max clamps per pixel are deleted. Straddling segments use the
//      unchanged r12 clamped path. Zero pad ring supplies OOB zeros.

typedef float vfloat4 __attribute__((ext_vector_type(4)));

constexpr int BATCH = 8;
constexpr int HI = 128, WI = 256;
constexpr int HO = 1024, WO = 2048;
constexpr size_t NPIX = (size_t)BATCH * HO * WO;   // 16777216 per output

// Quad image: Q[y+1][x+1] = (P[y][x], P[y][x+1], P[y+1][x], P[y+1][x+1]),
// P = zero-padded gt. Row index cy0+1 in [0,129], col cx0+1 in [0,257].
constexpr int QH = HI + 2;
constexpr int QW = WI + 2;
constexpr size_t QIMG = (size_t)QH * QW;           // quads per image

__global__ __launch_bounds__(256) void pad4_kernel(
    const float* __restrict__ gt, vfloat4* __restrict__ Q)
{
    const int i = blockIdx.x * 256 + threadIdx.x;  // over BATCH*QIMG
    if (i >= (int)(BATCH * QIMG)) return;
    const int b = i / (int)QIMG;
    const int r = i - b * (int)QIMG;
    const int y = r / QW - 1;                      // [-1, HI]
    const int x = r - (r / QW) * QW - 1;           // [-1, WI]
    const float* __restrict__ g = gt + (size_t)b * (HI * WI);
    auto val = [&](int yy, int xx) -> float {
        return (yy >= 0 && yy < HI && xx >= 0 && xx < WI)
                   ? g[yy * WI + xx] : 0.0f;
    };
    vfloat4 q = { val(y, x), val(y, x + 1), val(y + 1, x), val(y + 1, x + 1) };
    Q[i] = q;
}

__global__ __launch_bounds__(256) void stn_kernel(
    const float* __restrict__ gt,     // [B, HI, WI] (boxy path)
    const float* __restrict__ theta,  // [B, 6]
    const vfloat4* __restrict__ Q,    // quad images in d_ws
    float* __restrict__ out)          // [2, B, HO, WO] f32
{
    const int row = blockIdx.x;            // b*HO + h
    const int b = row >> 10;
    const int h = row & (HO - 1);
    const int t = threadIdx.x;
    const int w0 = t << 3;

    const float* tb = theta + b * 6;
    const float t0 = tb[0], t1 = tb[1], t2 = tb[2];
    const float t3 = tb[3], t4 = tb[4], t5 = tb[5];
    const float* __restrict__ gtb = gt + b * (HI * WI);
    // Pre-offset so index is cy0*QW + cx0 (pad ring at cy0=-1 / cx0=-1 ok).
    const vfloat4* __restrict__ Qb = Q + (size_t)b * QIMG + QW + 1;

    const float ys = (h + 0.5f) * (2.0f / (float)HO) - 1.0f;

    // ---------------- boxy: scalar per thread, broadcast to 8 px ----------------
    {
        const float gy2 = t4 * ys + t5;
        const float iy = ((gy2 + 1.0f) * (float)HO - 1.0f) * 0.5f;
        const float fy = floorf(iy);
        const float wy = iy - fy;
        const float vy0 = (fy >= 0.0f && fy <= (float)(HO - 1)) ? 1.0f : 0.0f;
        const float vy1 = (fy >= -1.0f && fy <= (float)(HO - 2)) ? 1.0f : 0.0f;
        const int y0 = ((int)fminf(fmaxf(fy,        0.0f), (float)(HO - 1))) >> 3;
        const int y1 = ((int)fminf(fmaxf(fy + 1.0f, 0.0f), (float)(HO - 1))) >> 3;
        const float s0 = gtb[y0 * WI + t];
        const float s1 = gtb[y1 * WI + t];
        const float byv = s0 * ((1.0f - wy) * vy0) + s1 * (wy * vy1);
        const vfloat4 vb = {byv, byv, byv, byv};
        vfloat4* dst = reinterpret_cast<vfloat4*>(out + NPIX + (size_t)row * WO + w0);
        __builtin_nontemporal_store(vb, dst);
        __builtin_nontemporal_store(vb, dst + 1);
    }

    // ---------------- box: 8 px bilinear via one quad load each ----------------
    const float xn0 = (w0 + 0.5f) * (2.0f / (float)WO) - 1.0f;
    const float gx0 = t0 * xn0 + (t1 * ys + t2);
    const float gy0 = t3 * xn0 + (t4 * ys + t5);
    const float ix0 = ((gx0 + 1.0f) * (float)WO - 1.0f) * 0.5f;  // step t0 per px
    const float iy0 = ((gy0 + 1.0f) * (float)HO - 1.0f) * 0.5f;  // step t3/2 per px
    const float dix = t0;
    const float diy = 0.5f * t3;

    const float ixe = ix0 + 7.0f * dix;
    const float iye = iy0 + 7.0f * diy;
    const float ixmin = fminf(ix0, ixe), ixmax = fmaxf(ix0, ixe);
    const float iymin = fminf(iy0, iye), iymax = fmaxf(iy0, iye);
    const bool segzero = (ixmax < -1.0f) || (ixmin >= (float)WO) ||
                         (iymax < -1.0f) || (iymin >= (float)HO);
    const bool segsafe = (ixmin >= -1.0f) && (ixmax < (float)WO) &&
                         (iymin >= -1.0f) && (iymax < (float)HO);

    float px[8];
    if (segzero) {
#pragma unroll
        for (int p = 0; p < 8; ++p) px[p] = 0.0f;
    } else if (segsafe) {
        // No clamps needed: xi in [-1, WO-1+1], shifts land in [-1,WI]/[-1,HI].
        vfloat4 q[8];
        float wx[8], wy[8];
        bool cxe[8], cye[8];
#pragma unroll
        for (int p = 0; p < 8; ++p) {
            const float ixp = fmaf((float)p, dix, ix0);
            const float iyp = fmaf((float)p, diy, iy0);
            const float fx = floorf(ixp), fy = floorf(iyp);
            wx[p] = ixp - fx;  wy[p] = iyp - fy;
            const int xi = (int)fx, yi = (int)fy;
            const int cx0 = xi >> 3;
            const int cx1 = (xi + 1) >> 3;
            const int cy0 = yi >> 3;
            const int cy1 = (yi + 1) >> 3;
            cxe[p] = (cx1 == cx0);
            cye[p] = (cy1 == cy0);
            q[p] = Qb[cy0 * QW + cx0];
        }
#pragma unroll
        for (int p = 0; p < 8; ++p) {
            const float a  = q[p].x;
            const float bb = cxe[p] ? q[p].x : q[p].y;   // P[cy0][cx1]
            const float c  = cye[p] ? q[p].x : q[p].z;   // P[cy1][cx0]
            const float dl = cxe[p] ? q[p].z : q[p].w;
            const float d  = cye[p] ? bb     : dl;       // P[cy1][cx1]
            const float h0 = fmaf(wx[p], bb - a, a);
            const float h1 = fmaf(wx[p], d - c,  c);
            px[p] = fmaf(wy[p], h1 - h0, h0);
        }
    } else {
        // General clamped path (rare: segment straddles a boundary) — r12 code.
        float ix = ix0, iy = iy0;
#pragma unroll
        for (int p = 0; p < 8; ++p) {
            const float fx = floorf(ix), fy = floorf(iy);
            const float wx = ix - fx,    wy = iy - fy;
            const int xi = (int)fx, yi = (int)fy;       // cvt saturates at extremes
            const int cx0 = min(max(xi >> 3,       -1), WI);
            const int cx1 = min(max((xi + 1) >> 3, -1), WI);
            const int cy0 = min(max(yi >> 3,       -1), HI);
            const int cy1 = min(max((yi + 1) >> 3, -1), HI);
            const vfloat4 q = Qb[cy0 * QW + cx0];
            const bool cxe = (cx1 == cx0);
            const bool cye = (cy1 == cy0);
            const float a  = q.x;
            const float bb = cxe ? q.x : q.y;           // P[cy0][cx1]
            const float c  = cye ? q.x : q.z;           // P[cy1][cx0]
            const float dl = cxe ? q.z : q.w;
            const float d  = cye ? bb  : dl;            // P[cy1][cx1]
            const float h0 = fmaf(wx, bb - a, a);
            const float h1 = fmaf(wx, d - c,  c);
            px[p] = fmaf(wy, h1 - h0, h0);
            ix += dix; iy += diy;
        }
    }
    vfloat4* dst = reinterpret_cast<vfloat4*>(out + (size_t)row * WO + w0);
    const vfloat4 v0 = {px[0], px[1], px[2], px[3]};
    const vfloat4 v1 = {px[4], px[5], px[6], px[7]};
    __builtin_nontemporal_store(v0, dst);
    __builtin_nontemporal_store(v1, dst + 1);
}

extern "C" void kernel_launch(void* const* d_in, const int* in_sizes, int n_in,
                              void* d_out, int out_size, void* d_ws, size_t ws_size,
                              hipStream_t stream) {
    const float* gt    = (const float*)d_in[0];
    const float* theta = (const float*)d_in[1];
    float* out = (float*)d_out;
    vfloat4* Q = (vfloat4*)d_ws;   // 8*130*258*16 B ~= 4.3 MB << ws_size

    const int qN = (int)(BATCH * QIMG);
    pad4_kernel<<<(qN + 255) / 256, 256, 0, stream>>>(gt, Q);
    stn_kernel<<<BATCH * HO, 256, 0, stream>>>(gt, theta, Q, out);
}

// Round 5
// 143.085 us; speedup vs baseline: 1.2148x; 1.1873x over previous
//
#include <hip/hip_runtime.h>
#include <stdint.h>

// Round 15: line-contiguous stores, no nontemporal.
// Base = r14 compute (quad-gather, zero-seg, segsafe de-clamp, pipelined
// loads), reorganized from 1x8-px to 2x4-px segments per thread so every
// wave store instruction is 64 lanes x 16 B = 1 KB CONTIGUOUS (r10-r14
// stored 16 B per lane at 32 B stride -> no instruction covered a full
// line; with nt L2-bypass that risks partial-line RMW at HBM on all
// 134 MB of output). nontemporal dropped: plain stores through L2.
// fp32 in / fp32 out. gt_up[y,x] == gt[y>>3, x>>3] (never materialized).

typedef float vfloat4 __attribute__((ext_vector_type(4)));

constexpr int BATCH = 8;
constexpr int HI = 128, WI = 256;
constexpr int HO = 1024, WO = 2048;
constexpr size_t NPIX = (size_t)BATCH * HO * WO;   // 16777216 per output

// Quad image: Q[y+1][x+1] = (P[y][x], P[y][x+1], P[y+1][x], P[y+1][x+1]),
// P = zero-padded gt. Row index cy0+1 in [0,129], col cx0+1 in [0,257].
constexpr int QH = HI + 2;
constexpr int QW = WI + 2;
constexpr size_t QIMG = (size_t)QH * QW;           // quads per image

__global__ __launch_bounds__(256) void pad4_kernel(
    const float* __restrict__ gt, vfloat4* __restrict__ Q)
{
    const int i = blockIdx.x * 256 + threadIdx.x;  // over BATCH*QIMG
    if (i >= (int)(BATCH * QIMG)) return;
    const int b = i / (int)QIMG;
    const int r = i - b * (int)QIMG;
    const int y = r / QW - 1;                      // [-1, HI]
    const int x = r - (r / QW) * QW - 1;           // [-1, WI]
    const float* __restrict__ g = gt + (size_t)b * (HI * WI);
    auto val = [&](int yy, int xx) -> float {
        return (yy >= 0 && yy < HI && xx >= 0 && xx < WI)
                   ? g[yy * WI + xx] : 0.0f;
    };
    vfloat4 q = { val(y, x), val(y, x + 1), val(y + 1, x), val(y + 1, x + 1) };
    Q[i] = q;
}

__global__ __launch_bounds__(256) void stn_kernel(
    const float* __restrict__ gt,     // [B, HI, WI] (boxy path)
    const float* __restrict__ theta,  // [B, 6]
    const vfloat4* __restrict__ Q,    // quad images in d_ws
    float* __restrict__ out)          // [2, B, HO, WO] f32
{
    const int row = blockIdx.x;            // b*HO + h
    const int b = row >> 10;
    const int h = row & (HO - 1);
    const int t = threadIdx.x;

    const float* tb = theta + b * 6;
    const float t0 = tb[0], t1 = tb[1], t2 = tb[2];
    const float t3 = tb[3], t4 = tb[4], t5 = tb[5];
    const float* __restrict__ gtb = gt + b * (HI * WI);
    // Pre-offset so index is cy0*QW + cx0 (pad ring at cy0=-1 / cx0=-1 ok).
    const vfloat4* __restrict__ Qb = Q + (size_t)b * QIMG + QW + 1;

    const float ys = (h + 0.5f) * (2.0f / (float)HO) - 1.0f;
    const float dix = t0;
    const float diy = 0.5f * t3;

    // boxy y-blend pieces (uniform over the row, independent of column):
    const float gy2 = t4 * ys + t5;
    const float iyy = ((gy2 + 1.0f) * (float)HO - 1.0f) * 0.5f;
    const float fyy = floorf(iyy);
    const float wyy = iyy - fyy;
    const float vy0 = (fyy >= 0.0f && fyy <= (float)(HO - 1)) ? 1.0f : 0.0f;
    const float vy1 = (fyy >= -1.0f && fyy <= (float)(HO - 2)) ? 1.0f : 0.0f;
    const int y0 = ((int)fminf(fmaxf(fyy,        0.0f), (float)(HO - 1))) >> 3;
    const int y1 = ((int)fminf(fmaxf(fyy + 1.0f, 0.0f), (float)(HO - 1))) >> 3;
    const float wA = (1.0f - wyy) * vy0;
    const float wB = wyy * vy1;

    float* const outrow  = out + (size_t)row * WO;
    float* const outrowy = out + NPIX + (size_t)row * WO;

#pragma unroll
    for (int s = 0; s < 2; ++s) {
        const int w0s = (s << 10) + (t << 2);   // 4-px segment base column

        // ---- boxy: one scalar per 4-px group (group never straddles a cell) ----
        {
            const int cell = w0s >> 3;
            const float s0 = gtb[y0 * WI + cell];
            const float s1 = gtb[y1 * WI + cell];
            const float byv = s0 * wA + s1 * wB;
            const vfloat4 vb = {byv, byv, byv, byv};
            *reinterpret_cast<vfloat4*>(outrowy + w0s) = vb;   // 1KB/wave contiguous
        }

        // ---- box: 4 px bilinear via one quad load each ----
        const float xn0 = (w0s + 0.5f) * (2.0f / (float)WO) - 1.0f;
        const float gx0 = t0 * xn0 + (t1 * ys + t2);
        const float gy0 = t3 * xn0 + (t4 * ys + t5);
        const float ix0 = ((gx0 + 1.0f) * (float)WO - 1.0f) * 0.5f;
        const float iy0 = ((gy0 + 1.0f) * (float)HO - 1.0f) * 0.5f;

        const float ixe = ix0 + 3.0f * dix;
        const float iye = iy0 + 3.0f * diy;
        const float ixmin = fminf(ix0, ixe), ixmax = fmaxf(ix0, ixe);
        const float iymin = fminf(iy0, iye), iymax = fmaxf(iy0, iye);
        const bool segzero = (ixmax < -1.0f) || (ixmin >= (float)WO) ||
                             (iymax < -1.0f) || (iymin >= (float)HO);
        const bool segsafe = (ixmin >= -1.0f) && (ixmax < (float)WO) &&
                             (iymin >= -1.0f) && (iymax < (float)HO);

        float px[4];
        if (segzero) {
#pragma unroll
            for (int p = 0; p < 4; ++p) px[p] = 0.0f;
        } else if (segsafe) {
            // No clamps: xi in [-1, WO-1], shifts land in [-1,WI]/[-1,HI];
            // pad ring supplies zeros.
            vfloat4 q[4];
            float wx[4], wy[4];
            bool cxe[4], cye[4];
#pragma unroll
            for (int p = 0; p < 4; ++p) {
                const float ixp = fmaf((float)p, dix, ix0);
                const float iyp = fmaf((float)p, diy, iy0);
                const float fx = floorf(ixp), fy = floorf(iyp);
                wx[p] = ixp - fx;  wy[p] = iyp - fy;
                const int xi = (int)fx, yi = (int)fy;
                const int cx0 = xi >> 3;
                const int cx1 = (xi + 1) >> 3;
                const int cy0 = yi >> 3;
                const int cy1 = (yi + 1) >> 3;
                cxe[p] = (cx1 == cx0);
                cye[p] = (cy1 == cy0);
                q[p] = Qb[cy0 * QW + cx0];
            }
#pragma unroll
            for (int p = 0; p < 4; ++p) {
                const float a  = q[p].x;
                const float bb = cxe[p] ? q[p].x : q[p].y;   // P[cy0][cx1]
                const float c  = cye[p] ? q[p].x : q[p].z;   // P[cy1][cx0]
                const float dl = cxe[p] ? q[p].z : q[p].w;
                const float d  = cye[p] ? bb     : dl;       // P[cy1][cx1]
                const float h0 = fmaf(wx[p], bb - a, a);
                const float h1 = fmaf(wx[p], d - c,  c);
                px[p] = fmaf(wy[p], h1 - h0, h0);
            }
        } else {
            // General clamped path (segment straddles a boundary) — r12 logic.
            float ix = ix0, iy = iy0;
#pragma unroll
            for (int p = 0; p < 4; ++p) {
                const float fx = floorf(ix), fy = floorf(iy);
                const float wx = ix - fx,    wy = iy - fy;
                const int xi = (int)fx, yi = (int)fy;    // cvt saturates at extremes
                const int cx0 = min(max(xi >> 3,       -1), WI);
                const int cx1 = min(max((xi + 1) >> 3, -1), WI);
                const int cy0 = min(max(yi >> 3,       -1), HI);
                const int cy1 = min(max((yi + 1) >> 3, -1), HI);
                const vfloat4 q = Qb[cy0 * QW + cx0];
                const bool cxe = (cx1 == cx0);
                const bool cye = (cy1 == cy0);
                const float a  = q.x;
                const float bb = cxe ? q.x : q.y;        // P[cy0][cx1]
                const float c  = cye ? q.x : q.z;        // P[cy1][cx0]
                const float dl = cxe ? q.z : q.w;
                const float d  = cye ? bb  : dl;         // P[cy1][cx1]
                const float h0 = fmaf(wx, bb - a, a);
                const float h1 = fmaf(wx, d - c,  c);
                px[p] = fmaf(wy, h1 - h0, h0);
                ix += dix; iy += diy;
            }
        }
        const vfloat4 v = {px[0], px[1], px[2], px[3]};
        *reinterpret_cast<vfloat4*>(outrow + w0s) = v;        // 1KB/wave contiguous
    }
}

extern "C" void kernel_launch(void* const* d_in, const int* in_sizes, int n_in,
                              void* d_out, int out_size, void* d_ws, size_t ws_size,
                              hipStream_t stream) {
    const float* gt    = (const float*)d_in[0];
    const float* theta = (const float*)d_in[1];
    float* out = (float*)d_out;
    vfloat4* Q = (vfloat4*)d_ws;   // 8*130*258*16 B ~= 4.3 MB << ws_size

    const int qN = (int)(BATCH * QIMG);
    pad4_kernel<<<(qN + 255) / 256, 256, 0, stream>>>(gt, Q);
    stn_kernel<<<BATCH * HO, 256, 0, stream>>>(gt, theta, Q, out);
}